// Round 2
// baseline (667.360 us; speedup 1.0000x reference)
//
#include <hip/hip_runtime.h>
#include <math.h>

#define NROWS 65536
#define DDIM 2048
#define NEXP 64
#define TOPK 8

constexpr int BM = 128;        // rows per block
constexpr int BK = 32;         // k-chunk
constexpr int NTH = 256;
constexpr int SX = BM + 4;     // xs stride (doubles)
constexpr int SW = NEXP + 4;   // ws stride (doubles)

// LDS: xs 32*132*8 = 33.8KB + ws 32*68*8 = 17.4KB + 512B accum = ~51.7KB
__global__ __launch_bounds__(NTH, 2)
void gate_kernel(const float* __restrict__ x, const float* __restrict__ W,
                 float* __restrict__ out_idx, float* __restrict__ out_gate,
                 float* __restrict__ g_psum, float* __restrict__ g_freq,
                 float* __restrict__ g_zsum)
{
    __shared__ double xs[BK][SX];
    __shared__ double ws[BK][SW];
    __shared__ float psum_s[NEXP];
    __shared__ float fcnt_s[NEXP];

    const int tid = threadIdx.x;
    const int row0 = blockIdx.x * BM;
    const int tx = tid & 7;    // expert group: experts tx*8 .. tx*8+7
    const int ty = tid >> 3;   // row group:    rows    ty*4 .. ty*4+3
    const int lane = tid & 63;

    if (tid < NEXP) { psum_s[tid] = 0.f; fcnt_s[tid] = 0.f; }

    double acc[4][8];
#pragma unroll
    for (int i = 0; i < 4; ++i)
#pragma unroll
        for (int e = 0; e < 8; ++e) acc[i][e] = 0.0;

    for (int k0 = 0; k0 < DDIM; k0 += BK) {
        // stage x tile: 128 rows x 32 k, fp32 load -> fp64 LDS (k-major)
#pragma unroll
        for (int it = 0; it < 4; ++it) {
            int q = tid + NTH * it;
            int r = q >> 3, c = q & 7;
            float4 v = *reinterpret_cast<const float4*>(
                &x[(size_t)(row0 + r) * DDIM + k0 + c * 4]);
            xs[c * 4 + 0][r] = (double)v.x;
            xs[c * 4 + 1][r] = (double)v.y;
            xs[c * 4 + 2][r] = (double)v.z;
            xs[c * 4 + 3][r] = (double)v.w;
        }
        // stage W tile: 64 experts x 32 k
#pragma unroll
        for (int it = 0; it < 2; ++it) {
            int q = tid + NTH * it;
            int e = q >> 3, c = q & 7;
            float4 v = *reinterpret_cast<const float4*>(
                &W[(size_t)e * DDIM + k0 + c * 4]);
            ws[c * 4 + 0][e] = (double)v.x;
            ws[c * 4 + 1][e] = (double)v.y;
            ws[c * 4 + 2][e] = (double)v.z;
            ws[c * 4 + 3][e] = (double)v.w;
        }
        __syncthreads();
#pragma unroll
        for (int kk = 0; kk < BK; ++kk) {
            double av[4], bv[8];
            *reinterpret_cast<double2*>(&av[0]) =
                *reinterpret_cast<const double2*>(&xs[kk][ty * 4]);
            *reinterpret_cast<double2*>(&av[2]) =
                *reinterpret_cast<const double2*>(&xs[kk][ty * 4 + 2]);
#pragma unroll
            for (int j = 0; j < 4; ++j)
                *reinterpret_cast<double2*>(&bv[j * 2]) =
                    *reinterpret_cast<const double2*>(&ws[kk][tx * 8 + j * 2]);
#pragma unroll
            for (int i = 0; i < 4; ++i)
#pragma unroll
                for (int e = 0; e < 8; ++e)
                    acc[i][e] = fma(av[i], bv[e], acc[i][e]);
        }
        __syncthreads();
    }

    // ---- epilogue: per row, the 8 lanes (same ty group) cooperate ----
    float zsq_acc = 0.f;
    float pcol[8];
#pragma unroll
    for (int e = 0; e < 8; ++e) pcol[e] = 0.f;

    for (int i = 0; i < 4; ++i) {
        // destructible copy for extraction; acc keeps originals for softmax
        double ld[8];
#pragma unroll
        for (int e = 0; e < 8; ++e) ld[e] = acc[i][e];

        double tv[TOPK];
        int ti[TOPK];
#pragma unroll
        for (int p = 0; p < TOPK; ++p) {
            // local argmax over this lane's 8 experts (ascending e => lowest idx on tie)
            double bv = -HUGE_VAL;
            int bgi = 127;
#pragma unroll
            for (int e = 0; e < 8; ++e) {
                if (ld[e] > bv) { bv = ld[e]; bgi = tx * 8 + e; }
            }
            // reduce across the 8-lane group; fp64 compare, lowest index on tie
#pragma unroll
            for (int m = 1; m < 8; m <<= 1) {
                double ov = __shfl_xor(bv, m, 8);
                int ogi = __shfl_xor(bgi, m, 8);
                if (ov > bv || (ov == bv && ogi < bgi)) { bv = ov; bgi = ogi; }
            }
            tv[p] = bv;
            ti[p] = bgi;
            if ((bgi >> 3) == tx) ld[bgi & 7] = -HUGE_VAL;  // winner lane removes
        }

        const double m0 = tv[0];
        // full softmax over this lane's 8 experts (fp32 from fp64 diffs)
        float pe[8];
        float ps = 0.f;
#pragma unroll
        for (int e = 0; e < 8; ++e) {
            pe[e] = expf((float)(acc[i][e] - m0));
            ps += pe[e];
        }
        float s = ps;
#pragma unroll
        for (int m = 1; m < 8; m <<= 1) s += __shfl_xor(s, m, 8);
        const float inv_s = 1.f / s;
#pragma unroll
        for (int e = 0; e < 8; ++e) pcol[e] += pe[e] * inv_s;

        // z-loss: (logaddexp(lse, log(EPS)))^2 ; lane 0 of group accumulates
        if (tx == 0) {
            float lsef = (float)m0 + logf(s);
            const float lb = -11.512925464970229f;  // log(1e-5)
            float mx = fmaxf(lsef, lb), mn = fminf(lsef, lb);
            float z = mx + log1pf(expf(mn - mx));
            zsq_acc += z * z;
        }

        // gates: lane tx handles rank position tx
        float ge = expf((float)(tv[tx] - m0));
        float gs = ge;
#pragma unroll
        for (int m = 1; m < 8; m <<= 1) gs += __shfl_xor(gs, m, 8);
        const size_t base = (size_t)(row0 + ty * 4 + i) * TOPK;
        out_idx[base + tx] = (float)ti[tx];
        out_gate[base + tx] = ge / gs;
        atomicAdd(&fcnt_s[ti[tx]], 1.f);
    }

    // z-loss wave reduction -> global
#pragma unroll
    for (int off = 32; off > 0; off >>= 1) zsq_acc += __shfl_down(zsq_acc, off, 64);
    if (lane == 0) atomicAdd(g_zsum, zsq_acc);

    // probs column sums -> shared -> global
#pragma unroll
    for (int e = 0; e < 8; ++e) atomicAdd(&psum_s[tx * 8 + e], pcol[e]);
    __syncthreads();
    if (tid < NEXP) {
        atomicAdd(&g_psum[tid], psum_s[tid]);
        atomicAdd(&g_freq[tid], fcnt_s[tid]);
    }
}

__global__ void finalize_kernel(const float* __restrict__ g_psum,
                                const float* __restrict__ g_freq,
                                const float* __restrict__ g_zsum,
                                float* __restrict__ out_loss)
{
    if (threadIdx.x == 0) {
        float sp = 0.f, sf = 0.f;
        for (int e = 0; e < NEXP; ++e) { sp += g_psum[e]; sf += g_freq[e]; }
        sp = fmaxf(sp, 1e-12f);
        sf = fmaxf(sf, 1e-12f);
        float sw = 0.f;
        for (int e = 0; e < NEXP; ++e) sw += (g_psum[e] / sp) * (g_freq[e] / sf);
        out_loss[0] = (float)NEXP * sw + 0.1f * (g_zsum[0] / (float)NROWS);
    }
}

extern "C" void kernel_launch(void* const* d_in, const int* in_sizes, int n_in,
                              void* d_out, int out_size, void* d_ws, size_t ws_size,
                              hipStream_t stream)
{
    const float* x = (const float*)d_in[0];
    const float* W = (const float*)d_in[1];
    float* out = (float*)d_out;
    float* out_idx  = out;                            // [65536*8] indices as float
    float* out_gate = out + (size_t)NROWS * TOPK;     // [65536*8] gates
    float* out_loss = out + (size_t)2 * NROWS * TOPK; // [1] loss

    float* acc = (float*)d_ws;  // psum[64] | freq[64] | zsum[1]
    hipMemsetAsync(acc, 0, 129 * sizeof(float), stream);
    gate_kernel<<<NROWS / BM, NTH, 0, stream>>>(
        x, W, out_idx, out_gate, acc, acc + NEXP, acc + 2 * NEXP);
    finalize_kernel<<<1, 64, 0, stream>>>(acc, acc + NEXP, acc + 2 * NEXP, out_loss);
}